// Round 19
// baseline (77.880 us; speedup 1.0000x reference)
//
#include <hip/hip_runtime.h>
#include <hip/hip_bf16.h>

#define NB 4096
#define DD 768
#define NKT 12            // K-tiles of BK=64 (fp8): 768/64
#define NBLK 256          // grid: 256 blocks = 1 per CU (128KB LDS) -> all co-resident

typedef float f32x4 __attribute__((ext_vector_type(4)));
typedef long i64x2 __attribute__((ext_vector_type(2)));
typedef unsigned int uint;

#define WAITVM(N) asm volatile("s_waitcnt vmcnt(" #N ")" ::: "memory")

// ---------------- init: zero stats + barrier/flag/ticket state (d_ws is poisoned 0xAA) ----------------
// scal[0..2]=stats, scal[3]=np acc (int), scal[4]=A acc (float).
// bars[0..383]: tree group counters; bars[384]: root; bars[448]: release epoch; bars[464]: done ticket;
// bars[512+p*16] p=0..31: panel-ready flags; bars[1024+by*16]: row tickets; bars[1536+bx*16]: col tickets.
__global__ void init_kernel(float* scal, uint* bars)
{
    int t = threadIdx.x;
    if (t < 16) scal[t] = 0.0f;
    bars[t] = 0u;
    bars[512 + t] = 0u;
    bars[1024 + t] = 0u;
    bars[1536 + t] = 0u;
}

// ---------------- tree grid barrier (phase-coherent; used once, phase=1) ----------------
__device__ __forceinline__ void grid_bar(uint* bars, uint phase, int rawb, int t)
{
    __syncthreads();
    if (t == 0) {
        int g = rawb & 15;
        uint prev = __hip_atomic_fetch_add(&bars[g * 16], 1u, __ATOMIC_ACQ_REL, __HIP_MEMORY_SCOPE_AGENT);
        if (prev == phase * 16u - 1u) {
            uint r = __hip_atomic_fetch_add(&bars[384], 1u, __ATOMIC_ACQ_REL, __HIP_MEMORY_SCOPE_AGENT);
            if (r == phase * 16u - 1u)
                __hip_atomic_store(&bars[448], phase, __ATOMIC_RELEASE, __HIP_MEMORY_SCOPE_AGENT);
        }
        while (__hip_atomic_load(&bars[448], __ATOMIC_RELAXED, __HIP_MEMORY_SCOPE_AGENT) < phase)
            __builtin_amdgcn_s_sleep(8);
        (void)__hip_atomic_load(&bars[448], __ATOMIC_ACQUIRE, __HIP_MEMORY_SCOPE_AGENT);
    }
    __syncthreads();
}

// ---------------- staging: one K-tile unit = A[256][64B] + B[256][64B] fp8 (32 KB), ring-4 ----------------
// Rows are 64 B (4 chunks of 16 B): logical chunk c of row r at phys chunk c ^ ((r>>1)&3);
// linear LDS dest, pre-swizzled global source chunk (rule #21). Measured 0 bank conflicts.
__device__ __forceinline__ void stage_range(
    unsigned char* ldsAll,
    const unsigned char* __restrict__ vhat8, const unsigned char* __restrict__ that8,
    int rowBase, int colBase, int T, int i0, int i1, int wid, int lane)
{
    int u = T & 3;
    const unsigned char* src = (wid >= 4) ? that8 : vhat8;
    int tb = (wid >= 4) ? colBase : rowBase;
    int w4 = wid & 3;
    int logc = (lane & 3) ^ ((lane >> 3) & 3);
    int rowIn = w4 * 64 + (lane >> 2);
    unsigned char* dbase = ldsAll + u * 32768 + ((wid >= 4) ? 16384 : 0) + w4 * 4096;
    #pragma unroll
    for (int i = i0; i <= i1; ++i) {
        const unsigned char* g = src + (size_t)(tb + rowIn + i * 16) * DD + T * 64 + logc * 16;
        __builtin_amdgcn_global_load_lds(
            (const __attribute__((address_space(1))) void*)g,
            (__attribute__((address_space(3))) void*)(dbase + i * 1024),
            16, 0, 0);
    }
}

// ---------------- fully fused; distributed final loss via panel tickets ----------------
__global__ __launch_bounds__(512, 2) void fused_kernel(
    const float* __restrict__ vf, const float* __restrict__ tf, const int* __restrict__ ids,
    unsigned char* __restrict__ vhat8, unsigned char* __restrict__ that8,
    float* scal, float* rs, float* cs, float* cntf, uint* bars,
    float* __restrict__ out)
{
    __shared__ unsigned char ldsAll[4 * 32768];   // 128 KB ring; unit 3 doubles as ids stage in phase 0
    __shared__ int idr[256], idc[256];
    __shared__ float red[24];
    __shared__ float rs_l[256], cs_l[256];
    __shared__ int bp[16];
    __shared__ float invT_sh, mf_sh;
    __shared__ int fin_sh;
    __shared__ float fra[8];

    int* np_acc = (int*)(scal + 3);
    float* A_acc = scal + 4;
    int rawb = blockIdx.x;
    int t = threadIdx.x, wid = t >> 6, lane = t & 63;

    // ===== phase 0a: normalize 32 rows/block -> fp8 e4m3, identity k-layout =====
    {
        f32x4 xr[4][3];
        uint* dsts[4];
        #pragma unroll
        for (int it = 0; it < 4; ++it) {
            int row = rawb * 32 + wid * 4 + it;
            const float* src;
            if (row < NB) { src = vf + (size_t)row * DD; dsts[it] = (uint*)(vhat8 + (size_t)row * DD); }
            else          { src = tf + (size_t)(row - NB) * DD; dsts[it] = (uint*)(that8 + (size_t)(row - NB) * DD); }
            xr[it][0] = *(const f32x4*)(src + lane * 4);
            xr[it][1] = *(const f32x4*)(src + 256 + lane * 4);
            xr[it][2] = *(const f32x4*)(src + 512 + lane * 4);
        }
        int idreg[8];
        #pragma unroll
        for (int i = 0; i < 8; ++i) idreg[i] = ids[t + i * 512];

        #pragma unroll
        for (int it = 0; it < 4; ++it) {
            float s = 0.f;
            #pragma unroll
            for (int c = 0; c < 3; ++c)
                s += xr[it][c][0]*xr[it][c][0] + xr[it][c][1]*xr[it][c][1]
                   + xr[it][c][2]*xr[it][c][2] + xr[it][c][3]*xr[it][c][3];
            #pragma unroll
            for (int off = 1; off < 64; off <<= 1) s += __shfl_xor(s, off, 64);
            float scale = 1.0f / sqrtf(s);
            #pragma unroll
            for (int c = 0; c < 3; ++c) {
                int p = __builtin_amdgcn_cvt_pk_fp8_f32(xr[it][c][0] * scale, xr[it][c][1] * scale, 0, false);
                p = __builtin_amdgcn_cvt_pk_fp8_f32(xr[it][c][2] * scale, xr[it][c][3] * scale, p, true);
                dsts[it][c * 64 + lane] = (uint)p;
            }
        }
        int* idsh = (int*)(ldsAll + 3 * 32768);
        #pragma unroll
        for (int i = 0; i < 8; ++i) idsh[t + i * 512] = idreg[i];
    }
    __syncthreads();
    // panel-ready release: this block's 32 rows belong to combined panel rawb/8 (0..31)
    if (t == 0)
        __hip_atomic_fetch_add(&bars[512 + (rawb >> 3) * 16], 1u, __ATOMIC_ACQ_REL, __HIP_MEMORY_SCOPE_AGENT);

    // ===== GEMM geometry =====
    int rg = rawb & 7, sq = rawb >> 3;
    int by = (rg >> 1) * 4 + (sq >> 3);
    int bx = (rg & 1) * 8 + (sq & 7);
    int rowBase = by * 256, colBase = bx * 256;
    int wr = wid >> 2, wc = wid & 3;
    int fr = lane & 15, g = lane >> 4;

    // ===== panel-ready poll: need vhat panel `by` and that panel `bx` (8 producers each) =====
    if (t == 0) {
        uint* fA = &bars[512 + by * 16];
        uint* fB = &bars[512 + (16 + bx) * 16];
        while (__hip_atomic_load(fA, __ATOMIC_RELAXED, __HIP_MEMORY_SCOPE_AGENT) < 8u)
            __builtin_amdgcn_s_sleep(4);
        while (__hip_atomic_load(fB, __ATOMIC_RELAXED, __HIP_MEMORY_SCOPE_AGENT) < 8u)
            __builtin_amdgcn_s_sleep(4);
        (void)__hip_atomic_load(fA, __ATOMIC_ACQUIRE, __HIP_MEMORY_SCOPE_AGENT);
        (void)__hip_atomic_load(fB, __ATOMIC_ACQUIRE, __HIP_MEMORY_SCOPE_AGENT);
    }
    __syncthreads();

    // ===== prologue staging issued NOW; cnt/np/zero/idr-idc overlap the in-flight loads =====
    stage_range(ldsAll, vhat8, that8, rowBase, colBase, 0, 0, 3, wid, lane);
    stage_range(ldsAll, vhat8, that8, rowBase, colBase, 1, 0, 3, wid, lane);
    stage_range(ldsAll, vhat8, that8, rowBase, colBase, 2, 0, 3, wid, lane);

    {
        int* idsh = (int*)(ldsAll + 3 * 32768);
        // cnt — 32 lanes per id, int4 LDS scan (unit 3; staging writes units 0-2 only)
        int sub = t >> 5, l32 = t & 31;
        int my = idsh[rawb * 16 + sub];
        const int4* idsh4 = (const int4*)idsh;
        int c = 0;
        #pragma unroll 8
        for (int j = l32; j < NB / 4; j += 32) {
            int4 v = idsh4[j];
            c += (v.x == my) + (v.y == my) + (v.z == my) + (v.w == my);
        }
        #pragma unroll
        for (int off = 16; off > 0; off >>= 1) c += __shfl_down(c, off, 32);
        if (l32 == 0) { cntf[rawb * 16 + sub] = (float)c; bp[sub] = c; }
        // idr/idc for the stats epilogue — from LDS, not global (unit 3 valid until stage T=3)
        if (t < 256) idr[t] = idsh[rowBase + t];
        else         idc[t - 256] = idsh[colBase + (t - 256)];
    }
    if (t < 32) rs[rawb * 32 + t] = 0.0f;   // zero rs+cs (contiguous 8192 floats)
    __syncthreads();
    if (t == 0) {
        int s = 0;
        #pragma unroll
        for (int i = 0; i < 16; ++i) s += bp[i];
        atomicAdd(np_acc, s);               // device-scope atomic: race-free np accumulation
    }
    WAITVM(8);                 // tile 0 staged (tiles 1,2 in flight)
    __builtin_amdgcn_s_barrier();

    // ===== GEMM: 256x256 tile, 8 waves, fp8 BK=64, ring-4, 2-phase =====
    f32x4 acc[8][4];
    #pragma unroll
    for (int m = 0; m < 8; ++m)
        #pragma unroll
        for (int n = 0; n < 4; ++n) acc[m][n] = (f32x4){0.f, 0.f, 0.f, 0.f};

    int pcoff = (g ^ ((fr >> 1) & 3)) * 16;
    int aoffB = (wr * 128 + fr) * 64 + pcoff;
    int boffB = 16384 + (wc * 64 + fr) * 64 + pcoff;

    for (int T = 0; T < NKT; ++T) {
        const unsigned char* U = ldsAll + (T & 3) * 32768;
        // phase A: reads(a0,bb) || stage half1(T+3) -> BAR -> MFMA m0..3 (x2 k-halves)
        i64x2 a0[4], bb[4];
        #pragma unroll
        for (int m = 0; m < 4; ++m) a0[m] = *(const i64x2*)(U + aoffB + m * 1024);
        #pragma unroll
        for (int n = 0; n < 4; ++n) bb[n] = *(const i64x2*)(U + boffB + n * 1024);
        if (T + 3 < NKT)
            stage_range(ldsAll, vhat8, that8, rowBase, colBase, T + 3, 0, 1, wid, lane);
        __builtin_amdgcn_s_barrier();
        __builtin_amdgcn_s_setprio(1);
        #pragma unroll
        for (int m = 0; m < 4; ++m)
            #pragma unroll
            for (int n = 0; n < 4; ++n) {
                acc[m][n] = __builtin_amdgcn_mfma_f32_16x16x32_fp8_fp8(a0[m][0], bb[n][0], acc[m][n], 0, 0, 0);
                acc[m][n] = __builtin_amdgcn_mfma_f32_16x16x32_fp8_fp8(a0[m][1], bb[n][1], acc[m][n], 0, 0, 0);
            }
        __builtin_amdgcn_s_setprio(0);
        __builtin_amdgcn_s_barrier();
        // phase B: reads(a1) || stage half2(T+3) -> BAR -> MFMA m4..7
        i64x2 a1[4];
        #pragma unroll
        for (int m = 0; m < 4; ++m) a1[m] = *(const i64x2*)(U + aoffB + (m + 4) * 1024);
        if (T + 3 < NKT)
            stage_range(ldsAll, vhat8, that8, rowBase, colBase, T + 3, 2, 3, wid, lane);
        __builtin_amdgcn_s_barrier();
        __builtin_amdgcn_s_setprio(1);
        #pragma unroll
        for (int m = 0; m < 4; ++m)
            #pragma unroll
            for (int n = 0; n < 4; ++n) {
                acc[m + 4][n] = __builtin_amdgcn_mfma_f32_16x16x32_fp8_fp8(a1[m][0], bb[n][0], acc[m + 4][n], 0, 0, 0);
                acc[m + 4][n] = __builtin_amdgcn_mfma_f32_16x16x32_fp8_fp8(a1[m][1], bb[n][1], acc[m + 4][n], 0, 0, 0);
            }
        __builtin_amdgcn_s_setprio(0);
        // tile boundary: T+1 staged; keep T+2/T+3 in flight (never vmcnt 0 mid-loop)
        if (T < NKT - 3)       { WAITVM(8); }
        else if (T == NKT - 3) { WAITVM(4); }
        else if (T == NKT - 2) { WAITVM(0); }
        __builtin_amdgcn_s_barrier();
    }

    // ===== stats: {total, S_mf, trace};  C/D: col=fr, row=g*4+reg [m89-verified] =====
    {
        float tsum = 0.f, msum = 0.f, dsum = 0.f;
        #pragma unroll
        for (int m = 0; m < 8; ++m) {
            int rl = wr * 128 + m * 16 + g * 4;
            #pragma unroll
            for (int n = 0; n < 4; ++n) {
                int cl = wc * 64 + n * 16 + fr;
                int colId = idc[cl];
                int gj = colBase + cl;
                #pragma unroll
                for (int r = 0; r < 4; ++r) {
                    float val = acc[m][n][r];
                    tsum += val;
                    if (idr[rl + r] == colId) msum += val;
                    if (rowBase + rl + r == gj) dsum += val;
                }
            }
        }
        #pragma unroll
        for (int off = 32; off > 0; off >>= 1) {
            tsum += __shfl_down(tsum, off, 64);
            msum += __shfl_down(msum, off, 64);
            dsum += __shfl_down(dsum, off, 64);
        }
        if (lane == 0) { red[wid] = tsum; red[8 + wid] = msum; red[16 + wid] = dsum; }
        __syncthreads();
        if (t == 0) {
            float s0 = 0.f, s1 = 0.f, s2 = 0.f;
            #pragma unroll
            for (int w = 0; w < 8; ++w) { s0 += red[w]; s1 += red[8 + w]; s2 += red[16 + w]; }
            atomicAdd(&scal[0], s0);
            atomicAdd(&scal[1], s1);
            atomicAdd(&scal[2], s2);
        }
    }
    if (t < 256) { rs_l[t] = 0.0f; cs_l[t] = 0.0f; }

    // ===== tree grid barrier (phase 1): stats + np complete =====
    grid_bar(bars, 1u, rawb, t);

    // ===== invT (t0 only; np via synchronized atomic) =====
    if (t == 0) {
        int npi = __hip_atomic_load(np_acc, __ATOMIC_RELAXED, __HIP_MEMORY_SCOPE_AGENT);
        float total = __hip_atomic_load(&scal[0], __ATOMIC_RELAXED, __HIP_MEMORY_SCOPE_AGENT);
        float mf    = __hip_atomic_load(&scal[1], __ATOMIC_RELAXED, __HIP_MEMORY_SCOPE_AGENT);
        float trace = __hip_atomic_load(&scal[2], __ATOMIC_RELAXED, __HIP_MEMORY_SCOPE_AGENT);
        float np = (float)npi;
        float pos_cnt = np - (float)NB;
        float neg_cnt = (float)NB * (float)NB - np;
        float pos_mean = (mf - trace) / fmaxf(1.0f, pos_cnt);
        float neg_mean = (total - mf) / fmaxf(1.0f, neg_cnt);
        float sep = pos_mean - neg_mean;
        float temp = 0.07f * (0.8f + 0.4f * expf(-2.0f * sep));
        temp = fminf(fmaxf(temp, 0.04f), 0.2f);
        invT_sh = 1.0f / temp;
        mf_sh = mf;
    }
    __syncthreads();
    float invT = invT_sh;

    // ===== exp((sim-1)/temp) row & col sums straight from registers =====
    #pragma unroll
    for (int m = 0; m < 8; ++m)
        #pragma unroll
        for (int n = 0; n < 4; ++n)
            #pragma unroll
            for (int r = 0; r < 4; ++r)
                acc[m][n][r] = __expf((acc[m][n][r] - 1.0f) * invT);
    #pragma unroll
    for (int m = 0; m < 8; ++m) {
        #pragma unroll
        for (int r = 0; r < 4; ++r) {
            float rp = 0.f;
            #pragma unroll
            for (int n = 0; n < 4; ++n) rp += acc[m][n][r];
            rp += __shfl_xor(rp, 1, 64);
            rp += __shfl_xor(rp, 2, 64);
            rp += __shfl_xor(rp, 4, 64);
            rp += __shfl_xor(rp, 8, 64);
            if (fr == 0) atomicAdd(&rs_l[wr * 128 + m * 16 + g * 4 + r], rp);
        }
    }
    #pragma unroll
    for (int n = 0; n < 4; ++n) {
        float cp = 0.f;
        #pragma unroll
        for (int m = 0; m < 8; ++m)
            #pragma unroll
            for (int r = 0; r < 4; ++r) cp += acc[m][n][r];
        cp += __shfl_xor(cp, 16, 64);
        cp += __shfl_xor(cp, 32, 64);
        if (g == 0) atomicAdd(&cs_l[wc * 64 + n * 16 + fr], cp);
    }
    __syncthreads();
    if (t < 256) {
        atomicAdd(&rs[rowBase + t], rs_l[t]);
        atomicAdd(&cs[colBase + t], cs_l[t]);
    }

    // ===== distributed final loss: row/col panel tickets (16 blocks each) =====
    __syncthreads();
    if (t == 0) {
        int k = 0;
        uint pr = __hip_atomic_fetch_add(&bars[1024 + by * 16], 1u, __ATOMIC_ACQ_REL, __HIP_MEMORY_SCOPE_AGENT);
        if (pr == 15u) k |= 1;
        uint pc = __hip_atomic_fetch_add(&bars[1536 + bx * 16], 1u, __ATOMIC_ACQ_REL, __HIP_MEMORY_SCOPE_AGENT);
        if (pc == 15u) k |= 2;
        fin_sh = k;
    }
    __syncthreads();
    int kfin = fin_sh;
    if (kfin == 0) return;

    // this block finalizes row panel `by` and/or col panel `bx` (256 values each, 512 threads)
    float partial = 0.f;
    if ((kfin & 1) && t < 256) partial += cntf[rowBase + t] * logf(rs[rowBase + t]);
    if ((kfin & 2) && t < 256) partial += cntf[colBase + t] * logf(cs[colBase + t]);
    #pragma unroll
    for (int off = 32; off > 0; off >>= 1) partial += __shfl_down(partial, off, 64);
    if (lane == 0) fra[wid] = partial;
    __syncthreads();
    if (t == 0) {
        float bsum = 0.f;
        #pragma unroll
        for (int w = 0; w < 8; ++w) bsum += fra[w];
        atomicAdd(A_acc, bsum);
        uint inc = (kfin == 3) ? 2u : 1u;
        uint prevd = __hip_atomic_fetch_add(&bars[464], inc, __ATOMIC_ACQ_REL, __HIP_MEMORY_SCOPE_AGENT);
        if (prevd + inc == 32u) {
            // all 32 panel partials in A_acc (acquire chain through done ticket)
            float A  = __hip_atomic_load(A_acc, __ATOMIC_RELAXED, __HIP_MEMORY_SCOPE_AGENT);
            int npi  = __hip_atomic_load(np_acc, __ATOMIC_RELAXED, __HIP_MEMORY_SCOPE_AGENT);
            float np = (float)npi;
            // lse_row[i] = 1/temp + log(rs[i]); v2t+t2v = sum cnt*(lse_r+lse_c) - 2*mf/temp
            out[0] = (A + 2.0f * invT_sh * (np - mf_sh)) / (2.0f * np);
        }
    }
}

extern "C" void kernel_launch(void* const* d_in, const int* in_sizes, int n_in,
                              void* d_out, int out_size, void* d_ws, size_t ws_size,
                              hipStream_t stream)
{
    const float* vf  = (const float*)d_in[0];
    const float* tf  = (const float*)d_in[1];
    const int*   ids = (const int*)d_in[2];

    float* ws_f = (float*)d_ws;
    float* scal = ws_f;                 // [0..2]=stats [3]=np acc [4]=A acc
    float* rs   = ws_f + 16;            // 4096  (cs contiguous after rs)
    float* cs   = ws_f + 16 + 4096;     // 4096
    float* cntf = ws_f + 16 + 8192;     // 4096
    uint* bars  = (uint*)(ws_f + 16 + 12800);  // 2048 words: tree + tickets + panel flags
    unsigned char* vhat8 = (unsigned char*)d_ws + 131072;   // 4096*768 fp8 = 3 MB
    unsigned char* that8 = vhat8 + (size_t)NB * DD;

    init_kernel<<<1, 512, 0, stream>>>(scal, bars);
    fused_kernel<<<NBLK, 512, 0, stream>>>(vf, tf, ids, vhat8, that8,
                                           scal, rs, cs, cntf, bars, (float*)d_out);
}

// Round 20
// 76.388 us; speedup vs baseline: 1.0195x; 1.0195x over previous
//
#include <hip/hip_runtime.h>
#include <hip/hip_bf16.h>

#define NB 4096
#define DD 768
#define NKT 12            // K-tiles of BK=64 (fp8): 768/64
#define NBLK 256          // grid: 256 blocks = 1 per CU (128KB LDS) -> all co-resident

typedef float f32x4 __attribute__((ext_vector_type(4)));
typedef long i64x2 __attribute__((ext_vector_type(2)));
typedef unsigned int uint;

#define WAITVM(N) asm volatile("s_waitcnt vmcnt(" #N ")" ::: "memory")

// ---------------- init: zero stats + barrier/flag state (d_ws is poisoned 0xAA) ----------------
// scal[0..2]=stats, scal[3]=np accumulator (int). bars[0..383]: tree group counters (g*16);
// bars[384]: root; bars[448]: release epoch; bars[464]: final ticket;
// bars[512 + p*16] p=0..31: panel-ready flags (8 producers each).
__global__ void init_kernel(float* scal, uint* bars)
{
    int t = threadIdx.x;
    if (t < 16) scal[t] = 0.0f;
    bars[t] = 0u;
    bars[512 + t] = 0u;
}

// ---------------- tree grid barrier (phase-coherent; used once, phase=1) ----------------
__device__ __forceinline__ void grid_bar(uint* bars, uint phase, int rawb, int t)
{
    __syncthreads();
    if (t == 0) {
        int g = rawb & 15;
        uint prev = __hip_atomic_fetch_add(&bars[g * 16], 1u, __ATOMIC_ACQ_REL, __HIP_MEMORY_SCOPE_AGENT);
        if (prev == phase * 16u - 1u) {
            uint r = __hip_atomic_fetch_add(&bars[384], 1u, __ATOMIC_ACQ_REL, __HIP_MEMORY_SCOPE_AGENT);
            if (r == phase * 16u - 1u)
                __hip_atomic_store(&bars[448], phase, __ATOMIC_RELEASE, __HIP_MEMORY_SCOPE_AGENT);
        }
        while (__hip_atomic_load(&bars[448], __ATOMIC_RELAXED, __HIP_MEMORY_SCOPE_AGENT) < phase)
            __builtin_amdgcn_s_sleep(8);
        (void)__hip_atomic_load(&bars[448], __ATOMIC_ACQUIRE, __HIP_MEMORY_SCOPE_AGENT);
    }
    __syncthreads();
}

// ---------------- staging: one K-tile unit = A[256][64B] + B[256][64B] fp8 (32 KB), ring-4 ----------------
// Rows are 64 B (4 chunks of 16 B): logical chunk c of row r at phys chunk c ^ ((r>>1)&3);
// linear LDS dest, pre-swizzled global source chunk (rule #21). Measured 0 bank conflicts.
__device__ __forceinline__ void stage_range(
    unsigned char* ldsAll,
    const unsigned char* __restrict__ vhat8, const unsigned char* __restrict__ that8,
    int rowBase, int colBase, int T, int i0, int i1, int wid, int lane)
{
    int u = T & 3;
    const unsigned char* src = (wid >= 4) ? that8 : vhat8;
    int tb = (wid >= 4) ? colBase : rowBase;
    int w4 = wid & 3;
    int logc = (lane & 3) ^ ((lane >> 3) & 3);
    int rowIn = w4 * 64 + (lane >> 2);
    unsigned char* dbase = ldsAll + u * 32768 + ((wid >= 4) ? 16384 : 0) + w4 * 4096;
    #pragma unroll
    for (int i = i0; i <= i1; ++i) {
        const unsigned char* g = src + (size_t)(tb + rowIn + i * 16) * DD + T * 64 + logc * 16;
        __builtin_amdgcn_global_load_lds(
            (const __attribute__((address_space(1))) void*)g,
            (__attribute__((address_space(3))) void*)(dbase + i * 1024),
            16, 0, 0);
    }
}

// ---------------- fully fused: normalize->fp8 | flags+poll | prologue||cnt+ids | GEMM+stats | tree-bar | exp | ticket | loss ----------------
__global__ __launch_bounds__(512, 2) void fused_kernel(
    const float* __restrict__ vf, const float* __restrict__ tf, const int* __restrict__ ids,
    unsigned char* __restrict__ vhat8, unsigned char* __restrict__ that8,
    float* scal, float* rs, float* cs, float* cntf, uint* bars,
    float* __restrict__ out)
{
    __shared__ unsigned char ldsAll[4 * 32768];   // 128 KB ring; unit 3 doubles as ids stage in phase 0
    __shared__ int idr[256], idc[256];
    __shared__ float red[24];
    __shared__ float rs_l[256], cs_l[256];
    __shared__ int bp[16];
    __shared__ float ra[8], rn[8];
    __shared__ float invT_sh, mf_sh;
    __shared__ uint tick_sh;

    int* np_acc = (int*)(scal + 3);   // zeroed by init; accumulated via device-scope atomics
    int rawb = blockIdx.x;
    int t = threadIdx.x, wid = t >> 6, lane = t & 63;

    // ===== phase 0a: normalize 32 rows/block -> fp8 e4m3, identity k-layout (plain f32x4 loads) =====
    {
        f32x4 xr[4][3];
        uint* dsts[4];
        #pragma unroll
        for (int it = 0; it < 4; ++it) {
            int row = rawb * 32 + wid * 4 + it;
            const float* src;
            if (row < NB) { src = vf + (size_t)row * DD; dsts[it] = (uint*)(vhat8 + (size_t)row * DD); }
            else          { src = tf + (size_t)(row - NB) * DD; dsts[it] = (uint*)(that8 + (size_t)(row - NB) * DD); }
            xr[it][0] = *(const f32x4*)(src + lane * 4);
            xr[it][1] = *(const f32x4*)(src + 256 + lane * 4);
            xr[it][2] = *(const f32x4*)(src + 512 + lane * 4);
        }
        int idreg[8];
        #pragma unroll
        for (int i = 0; i < 8; ++i) idreg[i] = ids[t + i * 512];

        #pragma unroll
        for (int it = 0; it < 4; ++it) {
            float s = 0.f;
            #pragma unroll
            for (int c = 0; c < 3; ++c)
                s += xr[it][c][0]*xr[it][c][0] + xr[it][c][1]*xr[it][c][1]
                   + xr[it][c][2]*xr[it][c][2] + xr[it][c][3]*xr[it][c][3];
            #pragma unroll
            for (int off = 1; off < 64; off <<= 1) s += __shfl_xor(s, off, 64);
            float scale = 1.0f / sqrtf(s);
            #pragma unroll
            for (int c = 0; c < 3; ++c) {
                int p = __builtin_amdgcn_cvt_pk_fp8_f32(xr[it][c][0] * scale, xr[it][c][1] * scale, 0, false);
                p = __builtin_amdgcn_cvt_pk_fp8_f32(xr[it][c][2] * scale, xr[it][c][3] * scale, p, true);
                dsts[it][c * 64 + lane] = (uint)p;
            }
        }
        // ids -> LDS unit 3 (ring units 0-2 stay free for the GEMM prologue)
        int* idsh = (int*)(ldsAll + 3 * 32768);
        #pragma unroll
        for (int i = 0; i < 8; ++i) idsh[t + i * 512] = idreg[i];
    }
    __syncthreads();
    // panel-ready release: this block's 32 rows belong to combined panel rawb/8 (0..31)
    if (t == 0)
        __hip_atomic_fetch_add(&bars[512 + (rawb >> 3) * 16], 1u, __ATOMIC_ACQ_REL, __HIP_MEMORY_SCOPE_AGENT);

    // ===== GEMM geometry =====
    int rg = rawb & 7, sq = rawb >> 3;
    int by = (rg >> 1) * 4 + (sq >> 3);
    int bx = (rg & 1) * 8 + (sq & 7);
    int rowBase = by * 256, colBase = bx * 256;
    int wr = wid >> 2, wc = wid & 3;
    int fr = lane & 15, g = lane >> 4;

    // ===== panel-ready poll: need vhat panel `by` and that panel `bx` (8 producers each) =====
    if (t == 0) {
        uint* fA = &bars[512 + by * 16];
        uint* fB = &bars[512 + (16 + bx) * 16];
        while (__hip_atomic_load(fA, __ATOMIC_RELAXED, __HIP_MEMORY_SCOPE_AGENT) < 8u)
            __builtin_amdgcn_s_sleep(4);
        while (__hip_atomic_load(fB, __ATOMIC_RELAXED, __HIP_MEMORY_SCOPE_AGENT) < 8u)
            __builtin_amdgcn_s_sleep(4);
        (void)__hip_atomic_load(fA, __ATOMIC_ACQUIRE, __HIP_MEMORY_SCOPE_AGENT);
        (void)__hip_atomic_load(fB, __ATOMIC_ACQUIRE, __HIP_MEMORY_SCOPE_AGENT);
    }
    __syncthreads();

    // ===== prologue staging issued NOW; cnt/np/zero/idr-idc overlap the in-flight loads =====
    stage_range(ldsAll, vhat8, that8, rowBase, colBase, 0, 0, 3, wid, lane);
    stage_range(ldsAll, vhat8, that8, rowBase, colBase, 1, 0, 3, wid, lane);
    stage_range(ldsAll, vhat8, that8, rowBase, colBase, 2, 0, 3, wid, lane);

    {
        int* idsh = (int*)(ldsAll + 3 * 32768);
        // cnt — 32 lanes per id, int4 LDS scan (unit 3; staging writes units 0-2 only)
        int sub = t >> 5, l32 = t & 31;
        int my = idsh[rawb * 16 + sub];
        const int4* idsh4 = (const int4*)idsh;
        int c = 0;
        #pragma unroll 8
        for (int j = l32; j < NB / 4; j += 32) {
            int4 v = idsh4[j];
            c += (v.x == my) + (v.y == my) + (v.z == my) + (v.w == my);
        }
        #pragma unroll
        for (int off = 16; off > 0; off >>= 1) c += __shfl_down(c, off, 32);
        if (l32 == 0) { cntf[rawb * 16 + sub] = (float)c; bp[sub] = c; }
        // idr/idc for the stats epilogue — from LDS, not global (unit 3 valid until stage T=3,
        // which issues only after the pre-loop barrier)
        if (t < 256) idr[t] = idsh[rowBase + t];
        else         idc[t - 256] = idsh[colBase + (t - 256)];
    }
    if (t < 32) rs[rawb * 32 + t] = 0.0f;   // zero rs+cs (contiguous 8192 floats)
    __syncthreads();
    if (t == 0) {
        int s = 0;
        #pragma unroll
        for (int i = 0; i < 16; ++i) s += bp[i];
        atomicAdd(np_acc, s);               // device-scope atomic: race-free np accumulation
    }
    WAITVM(8);                 // tile 0 staged (tiles 1,2 in flight)
    __builtin_amdgcn_s_barrier();

    // ===== GEMM: 256x256 tile, 8 waves, fp8 BK=64, ring-4, 2-phase =====
    f32x4 acc[8][4];
    #pragma unroll
    for (int m = 0; m < 8; ++m)
        #pragma unroll
        for (int n = 0; n < 4; ++n) acc[m][n] = (f32x4){0.f, 0.f, 0.f, 0.f};

    int pcoff = (g ^ ((fr >> 1) & 3)) * 16;
    int aoffB = (wr * 128 + fr) * 64 + pcoff;
    int boffB = 16384 + (wc * 64 + fr) * 64 + pcoff;

    for (int T = 0; T < NKT; ++T) {
        const unsigned char* U = ldsAll + (T & 3) * 32768;
        // phase A: reads(a0,bb) || stage half1(T+3) -> BAR -> MFMA m0..3 (x2 k-halves)
        i64x2 a0[4], bb[4];
        #pragma unroll
        for (int m = 0; m < 4; ++m) a0[m] = *(const i64x2*)(U + aoffB + m * 1024);
        #pragma unroll
        for (int n = 0; n < 4; ++n) bb[n] = *(const i64x2*)(U + boffB + n * 1024);
        if (T + 3 < NKT)
            stage_range(ldsAll, vhat8, that8, rowBase, colBase, T + 3, 0, 1, wid, lane);
        __builtin_amdgcn_s_barrier();
        __builtin_amdgcn_s_setprio(1);
        #pragma unroll
        for (int m = 0; m < 4; ++m)
            #pragma unroll
            for (int n = 0; n < 4; ++n) {
                acc[m][n] = __builtin_amdgcn_mfma_f32_16x16x32_fp8_fp8(a0[m][0], bb[n][0], acc[m][n], 0, 0, 0);
                acc[m][n] = __builtin_amdgcn_mfma_f32_16x16x32_fp8_fp8(a0[m][1], bb[n][1], acc[m][n], 0, 0, 0);
            }
        __builtin_amdgcn_s_setprio(0);
        __builtin_amdgcn_s_barrier();
        // phase B: reads(a1) || stage half2(T+3) -> BAR -> MFMA m4..7
        i64x2 a1[4];
        #pragma unroll
        for (int m = 0; m < 4; ++m) a1[m] = *(const i64x2*)(U + aoffB + (m + 4) * 1024);
        if (T + 3 < NKT)
            stage_range(ldsAll, vhat8, that8, rowBase, colBase, T + 3, 2, 3, wid, lane);
        __builtin_amdgcn_s_barrier();
        __builtin_amdgcn_s_setprio(1);
        #pragma unroll
        for (int m = 0; m < 4; ++m)
            #pragma unroll
            for (int n = 0; n < 4; ++n) {
                acc[m + 4][n] = __builtin_amdgcn_mfma_f32_16x16x32_fp8_fp8(a1[m][0], bb[n][0], acc[m + 4][n], 0, 0, 0);
                acc[m + 4][n] = __builtin_amdgcn_mfma_f32_16x16x32_fp8_fp8(a1[m][1], bb[n][1], acc[m + 4][n], 0, 0, 0);
            }
        __builtin_amdgcn_s_setprio(0);
        // tile boundary: T+1 staged; keep T+2/T+3 in flight (never vmcnt 0 mid-loop)
        if (T < NKT - 3)       { WAITVM(8); }
        else if (T == NKT - 3) { WAITVM(4); }
        else if (T == NKT - 2) { WAITVM(0); }
        __builtin_amdgcn_s_barrier();
    }

    // ===== stats: {total, S_mf, trace};  C/D: col=fr, row=g*4+reg [m89-verified] =====
    {
        float tsum = 0.f, msum = 0.f, dsum = 0.f;
        #pragma unroll
        for (int m = 0; m < 8; ++m) {
            int rl = wr * 128 + m * 16 + g * 4;
            #pragma unroll
            for (int n = 0; n < 4; ++n) {
                int cl = wc * 64 + n * 16 + fr;
                int colId = idc[cl];
                int gj = colBase + cl;
                #pragma unroll
                for (int r = 0; r < 4; ++r) {
                    float val = acc[m][n][r];
                    tsum += val;
                    if (idr[rl + r] == colId) msum += val;
                    if (rowBase + rl + r == gj) dsum += val;
                }
            }
        }
        #pragma unroll
        for (int off = 32; off > 0; off >>= 1) {
            tsum += __shfl_down(tsum, off, 64);
            msum += __shfl_down(msum, off, 64);
            dsum += __shfl_down(dsum, off, 64);
        }
        if (lane == 0) { red[wid] = tsum; red[8 + wid] = msum; red[16 + wid] = dsum; }
        __syncthreads();
        if (t == 0) {
            float s0 = 0.f, s1 = 0.f, s2 = 0.f;
            #pragma unroll
            for (int w = 0; w < 8; ++w) { s0 += red[w]; s1 += red[8 + w]; s2 += red[16 + w]; }
            atomicAdd(&scal[0], s0);
            atomicAdd(&scal[1], s1);
            atomicAdd(&scal[2], s2);
        }
    }
    if (t < 256) { rs_l[t] = 0.0f; cs_l[t] = 0.0f; }

    // ===== tree grid barrier (phase 1): stats + np complete =====
    grid_bar(bars, 1u, rawb, t);

    // ===== invT (t0 only; np via synchronized atomic) =====
    if (t == 0) {
        int npi = __hip_atomic_load(np_acc, __ATOMIC_RELAXED, __HIP_MEMORY_SCOPE_AGENT);
        float total = __hip_atomic_load(&scal[0], __ATOMIC_RELAXED, __HIP_MEMORY_SCOPE_AGENT);
        float mf    = __hip_atomic_load(&scal[1], __ATOMIC_RELAXED, __HIP_MEMORY_SCOPE_AGENT);
        float trace = __hip_atomic_load(&scal[2], __ATOMIC_RELAXED, __HIP_MEMORY_SCOPE_AGENT);
        float np = (float)npi;
        float pos_cnt = np - (float)NB;
        float neg_cnt = (float)NB * (float)NB - np;
        float pos_mean = (mf - trace) / fmaxf(1.0f, pos_cnt);
        float neg_mean = (total - mf) / fmaxf(1.0f, neg_cnt);
        float sep = pos_mean - neg_mean;
        float temp = 0.07f * (0.8f + 0.4f * expf(-2.0f * sep));
        temp = fminf(fmaxf(temp, 0.04f), 0.2f);
        invT_sh = 1.0f / temp;
        mf_sh = mf;
    }
    __syncthreads();
    float invT = invT_sh;

    // ===== exp((sim-1)/temp) row & col sums straight from registers =====
    #pragma unroll
    for (int m = 0; m < 8; ++m)
        #pragma unroll
        for (int n = 0; n < 4; ++n)
            #pragma unroll
            for (int r = 0; r < 4; ++r)
                acc[m][n][r] = __expf((acc[m][n][r] - 1.0f) * invT);
    #pragma unroll
    for (int m = 0; m < 8; ++m) {
        #pragma unroll
        for (int r = 0; r < 4; ++r) {
            float rp = 0.f;
            #pragma unroll
            for (int n = 0; n < 4; ++n) rp += acc[m][n][r];
            rp += __shfl_xor(rp, 1, 64);
            rp += __shfl_xor(rp, 2, 64);
            rp += __shfl_xor(rp, 4, 64);
            rp += __shfl_xor(rp, 8, 64);
            if (fr == 0) atomicAdd(&rs_l[wr * 128 + m * 16 + g * 4 + r], rp);
        }
    }
    #pragma unroll
    for (int n = 0; n < 4; ++n) {
        float cp = 0.f;
        #pragma unroll
        for (int m = 0; m < 8; ++m)
            #pragma unroll
            for (int r = 0; r < 4; ++r) cp += acc[m][n][r];
        cp += __shfl_xor(cp, 16, 64);
        cp += __shfl_xor(cp, 32, 64);
        if (g == 0) atomicAdd(&cs_l[wc * 64 + n * 16 + fr], cp);
    }
    __syncthreads();
    if (t < 256) {
        atomicAdd(&rs[rowBase + t], rs_l[t]);
        atomicAdd(&cs[colBase + t], cs_l[t]);
    }

    // ===== last-block ticket: the 256th arriver runs the final loss; everyone else exits =====
    __syncthreads();
    if (t == 0) {
        uint prev = __hip_atomic_fetch_add(&bars[464], 1u, __ATOMIC_ACQ_REL, __HIP_MEMORY_SCOPE_AGENT);
        tick_sh = prev;
    }
    __syncthreads();
    if (tick_sh != NBLK - 1) return;

    // ===== final loss (last-arriving block; its ACQ_REL RMW synchronized with all others) =====
    {
        float a = 0.f, npl = 0.f;
        for (int i = t; i < NB; i += 512) {
            float cf = cntf[i];
            a += cf * (logf(rs[i]) + logf(cs[i]));
            npl += cf;
        }
        #pragma unroll
        for (int off = 32; off > 0; off >>= 1) {
            a += __shfl_down(a, off, 64);
            npl += __shfl_down(npl, off, 64);
        }
        if (lane == 0) { ra[wid] = a; rn[wid] = npl; }
        __syncthreads();
        if (t == 0) {
            float A = 0.f, np = 0.f;
            #pragma unroll
            for (int w = 0; w < 8; ++w) { A += ra[w]; np += rn[w]; }
            // lse_row[i] = 1/temp + log(rs[i]); v2t+t2v = sum cnt*(lse_r+lse_c) - 2*mf/temp
            out[0] = (A + 2.0f * invT_sh * (np - mf_sh)) / (2.0f * np);
        }
    }
}

extern "C" void kernel_launch(void* const* d_in, const int* in_sizes, int n_in,
                              void* d_out, int out_size, void* d_ws, size_t ws_size,
                              hipStream_t stream)
{
    const float* vf  = (const float*)d_in[0];
    const float* tf  = (const float*)d_in[1];
    const int*   ids = (const int*)d_in[2];

    float* ws_f = (float*)d_ws;
    float* scal = ws_f;                 // [0]=total [1]=S_mf [2]=trace [3]=np accumulator (int)
    float* rs   = ws_f + 16;            // 4096  (cs contiguous after rs)
    float* cs   = ws_f + 16 + 4096;     // 4096
    float* cntf = ws_f + 16 + 8192;     // 4096
    uint* bars  = (uint*)(ws_f + 16 + 12800);  // 1024 words: tree barrier + ticket + panel flags
    unsigned char* vhat8 = (unsigned char*)d_ws + 131072;   // 4096*768 fp8 = 3 MB
    unsigned char* that8 = vhat8 + (size_t)NB * DD;

    init_kernel<<<1, 512, 0, stream>>>(scal, bars);
    fused_kernel<<<NBLK, 512, 0, stream>>>(vf, tf, ids, vhat8, that8,
                                           scal, rs, cs, cntf, bars, (float*)d_out);
}